// Round 6
// baseline (568.844 us; speedup 1.0000x reference)
//
#include <hip/hip_runtime.h>

// RelMultiHeadAttention (Transformer-XL) on gfx950.
// B=2, S=2048, D=1024, H=16, hd=64.
// R12: R11 (wave-local in-register softmax->PV) with the spill fixed and
// strips double-buffered. R11's allocator kept 64 VGPRs (chasing 8 waves/EU)
// and spilled vf/af to scratch (WRITE_SIZE 8->40MB). amdgpu_waves_per_eu(4,4)
// caps occupancy at 4 waves/EU (= measured ~3.5 blocks/CU anyway) so the
// allocator uses up to 128 VGPRs spill-free. Strips are double-buffered
// (36.9KB LDS, 4 blocks/CU): ONE barrier per pass (write buf[p&1], barrier,
// read it while next pass writes the other buffer; program order makes this
// safe). 32->16 barrier convoys; waves can drift a full pass apart.

typedef float  floatx4 __attribute__((ext_vector_type(4)));
typedef __bf16 bf16x8  __attribute__((ext_vector_type(8)));
typedef _Float16 f16x8 __attribute__((ext_vector_type(8)));
typedef _Float16 f16x4 __attribute__((ext_vector_type(4)));

#define LSTR 40   // proj-GEMM LDS row stride (bf16): conflict-free b128

struct GP {
  const void* A;
  const __bf16* B;
  int lda, ldb, K;
  float* outF;
  __bf16* out1;
  const float* bias;
};

// Output projection only (attn bf16 @ Wo + bo -> f32)
__global__ void __launch_bounds__(256) gemm_o(GP p) {
  __shared__ __bf16 lA[128 * LSTR];
  __shared__ __bf16 lB[128 * LSTR];
  const int t = threadIdx.x;
  const int wave = t >> 6, lane = t & 63;
  const int m0 = blockIdx.y * 128, n0 = blockIdx.x * 128;
  const int srow = t >> 2, scol = (t & 3) << 3;
  const __bf16* Ab = (const __bf16*)p.A;
  const __bf16* Bb = p.B;

  floatx4 acc[4][4];
#pragma unroll
  for (int i = 0; i < 4; i++)
#pragma unroll
    for (int j = 0; j < 4; j++) acc[i][j] = floatx4{0.f, 0.f, 0.f, 0.f};

  const int lr = lane & 15, lq = lane >> 4;
  const int wr = (wave >> 1) << 6, wc = (wave & 1) << 6;

  for (int kk = 0; kk < p.K; kk += 32) {
#pragma unroll
    for (int h2 = 0; h2 < 2; h2++) {
      int r = srow + (h2 << 6);
      const __bf16* ap = Ab + (long)(m0 + r) * p.lda + kk + scol;
      *(bf16x8*)&lA[r * LSTR + scol] = *(const bf16x8*)ap;
      const __bf16* bp = Bb + (long)(n0 + r) * p.ldb + kk + scol;
      *(bf16x8*)&lB[r * LSTR + scol] = *(const bf16x8*)bp;
    }
    __syncthreads();
    bf16x8 aF[4], bF[4];
#pragma unroll
    for (int i = 0; i < 4; i++)
      aF[i] = *(bf16x8*)&lA[(wr + i * 16 + lr) * LSTR + (lq << 3)];
#pragma unroll
    for (int i = 0; i < 4; i++)
      bF[i] = *(bf16x8*)&lB[(wc + i * 16 + lr) * LSTR + (lq << 3)];
#pragma unroll
    for (int i = 0; i < 4; i++)
#pragma unroll
      for (int j = 0; j < 4; j++)
        acc[i][j] = __builtin_amdgcn_mfma_f32_16x16x32_bf16(aF[i], bF[j], acc[i][j], 0, 0, 0);
    __syncthreads();
  }
#pragma unroll
  for (int i = 0; i < 4; i++)
#pragma unroll
    for (int j = 0; j < 4; j++) {
      int col = n0 + wc + j * 16 + lr;
#pragma unroll
      for (int g = 0; g < 4; g++) {
        int rl = m0 + wr + i * 16 + (lq << 2) + g;
        p.outF[(long)rl * 1024 + col] = acc[i][j][g] + p.bias[col];
      }
    }
}

// ---- merged Q/K/V/R projection: one launch, job table ----------------------
struct QPAll {
  const float *qin, *kvin, *pos;
  const __bf16 *Wtq, *Wtk, *Wtv, *Wtr;
  const float *bq, *bk, *bv, *rrb;
  __bf16 *qb, *qrr, *kb, *rb;
  _Float16 *vt;
};

__global__ void __launch_bounds__(256, 3) qkvr_k(QPAll p) {
  __shared__ __bf16 lA[128 * LSTR];
  __shared__ __bf16 lB[128 * LSTR];
  const int jb = blockIdx.x;
  const int job = (jb >= 768) ? 3 : (jb >> 8);
  const int local = jb - ((job == 3) ? 768 : (job << 8));
  const int m0 = (local >> 3) * 128, n0 = (local & 7) * 128;

  const float* A; const __bf16* B; const float* bias;
  if (job == 0)      { A = p.qin;  B = p.Wtq; bias = p.bq; }
  else if (job == 1) { A = p.kvin; B = p.Wtk; bias = p.bk; }
  else if (job == 2) { A = p.kvin; B = p.Wtv; bias = p.bv; }
  else               { A = p.pos;  B = p.Wtr; bias = nullptr; }

  const int t = threadIdx.x;
  const int wave = t >> 6, lane = t & 63;
  const int srow = t >> 2, scol = (t & 3) << 3;

  floatx4 acc[4][4];
#pragma unroll
  for (int i = 0; i < 4; i++)
#pragma unroll
    for (int j = 0; j < 4; j++) acc[i][j] = floatx4{0.f, 0.f, 0.f, 0.f};

  const int lr = lane & 15, lq = lane >> 4;
  const int wr = (wave >> 1) << 6, wc = (wave & 1) << 6;

  for (int kk = 0; kk < 1024; kk += 32) {
#pragma unroll
    for (int h2 = 0; h2 < 2; h2++) {
      int r = srow + (h2 << 6);
      const float* ap = A + (long)(m0 + r) * 1024 + kk + scol;
      float4 f0 = *(const float4*)ap;
      float4 f1 = *(const float4*)(ap + 4);
      bf16x8 o;
      o[0] = (__bf16)f0.x; o[1] = (__bf16)f0.y; o[2] = (__bf16)f0.z; o[3] = (__bf16)f0.w;
      o[4] = (__bf16)f1.x; o[5] = (__bf16)f1.y; o[6] = (__bf16)f1.z; o[7] = (__bf16)f1.w;
      *(bf16x8*)&lA[r * LSTR + scol] = o;
      const __bf16* bp = B + (long)(n0 + r) * 1024 + kk + scol;
      *(bf16x8*)&lB[r * LSTR + scol] = *(const bf16x8*)bp;
    }
    __syncthreads();
    bf16x8 aF[4], bF[4];
#pragma unroll
    for (int i = 0; i < 4; i++)
      aF[i] = *(bf16x8*)&lA[(wr + i * 16 + lr) * LSTR + (lq << 3)];
#pragma unroll
    for (int i = 0; i < 4; i++)
      bF[i] = *(bf16x8*)&lB[(wc + i * 16 + lr) * LSTR + (lq << 3)];
#pragma unroll
    for (int i = 0; i < 4; i++)
#pragma unroll
      for (int j = 0; j < 4; j++)
        acc[i][j] = __builtin_amdgcn_mfma_f32_16x16x32_bf16(aF[i], bF[j], acc[i][j], 0, 0, 0);
    __syncthreads();
  }

  // epilogue per job; C/D: col=lane&15, row=(lane>>4)*4+reg
#pragma unroll
  for (int i = 0; i < 4; i++)
#pragma unroll
    for (int j = 0; j < 4; j++) {
      int col = n0 + wc + j * 16 + lr;
#pragma unroll
      for (int g = 0; g < 4; g++) {
        int rl = m0 + wr + i * 16 + (lq << 2) + g;
        float val = acc[i][j][g];
        int hh = col >> 6, d = col & 63;
        if (job == 3) {
          long dst = (((long)hh * 2048 + rl) << 6) + d;
          p.rb[dst] = (__bf16)val;
        } else {
          int bb = rl >> 11, s = rl & 2047;
          float v = val + bias[col];
          if (job == 0) {
            long dst = (((long)(bb * 16 + hh) * 2048 + s) << 6) + d;
            p.qb[dst] = (__bf16)v;
            p.qrr[dst] = (__bf16)(v + p.rrb[col]);
          } else if (job == 1) {
            long dst = (((long)(bb * 16 + hh) * 2048 + s) << 6) + d;
            p.kb[dst] = (__bf16)v;
          } else {
            long dst = ((((long)(bb * 16 + hh)) << 6) + d) * 2048 + s;
            p.vt[dst] = (_Float16)v;
          }
        }
      }
    }
}

__global__ void __launch_bounds__(256) cb_k(const __bf16* kb, const float* rwb, float* cb) {
  long id = (long)blockIdx.x * 256 + threadIdx.x;  // 32*2048
  int z = (int)(id >> 11);
  int j = (int)(id & 2047);
  int h = z & 15;
  const __bf16* kp = kb + (((long)z * 2048 + j) << 6);
  float s = 0.f;
#pragma unroll
  for (int c = 0; c < 8; c++) {
    bf16x8 kv = *(const bf16x8*)(kp + c * 8);
#pragma unroll
    for (int e = 0; e < 8; e++) s += rwb[h * 64 + c * 8 + e] * (float)kv[e];
  }
  cb[id] = s * 0.125f;
}

// All five weight transposes in one launch: 5 x 256 tiles.
struct TRP { const float* src[5]; __bf16* dst[5]; };
__global__ void __launch_bounds__(256) tr_cvt_all(TRP p) {
  __shared__ float tile[64][65];
  const int id = blockIdx.x;
  const int which = id >> 8;
  const int local = id & 255;
  const int bx = local & 15, by = local >> 4;
  const float* src = p.src[which];
  __bf16* dst = p.dst[which];
  int tx = threadIdx.x & 63, ty = threadIdx.x >> 6;
#pragma unroll
  for (int r = ty; r < 64; r += 4)
    tile[r][tx] = src[(long)(by * 64 + r) * 1024 + bx * 64 + tx];
  __syncthreads();
#pragma unroll
  for (int r = ty; r < 64; r += 4)
    dst[(long)(bx * 64 + r) * 1024 + by * 64 + tx] = (__bf16)tile[tx][r];
}

// -------- fused scores + rel-shift + softmax + PV: 4-wave blocks -----------
// 32 q-rows/block, 16 j-passes of width 128, DOUBLE-BUFFERED strips.
// Per pass: qk+x MFMA + boundary copy into buf[kp&1] -> barrier -> V prefetch
// + in-register exp + PV (reads buf[kp&1], while next pass writes the other).
#define QW 128
#define QSTR3 136                         // row stride f16; 2-way bank (free)
#define SM_ONE (32 * QSTR3 * 2)           // 8704 B per strip
#define SM_BUF (2 * SM_ONE)               // qk+x per buffer
#define FUSED_SMEM (2 * SM_BUF + 2048)    // 36864 B -> 4 blocks/CU

__global__ void __launch_bounds__(256)
__attribute__((amdgpu_waves_per_eu(4, 4)))
fused_k(const __bf16* __restrict__ qb,
        const __bf16* __restrict__ qrr,
        const __bf16* __restrict__ kb,
        const _Float16* __restrict__ vt,
        const __bf16* __restrict__ rb,
        const float* __restrict__ cb,
        __bf16* __restrict__ attnb) {
  extern __shared__ char smem[];
  _Float16* xB = (_Float16*)(smem + 2 * SM_BUF);   // [1024] boundary row
  __shared__ float sPs[32][2];   // per-row partial sums (sl halves)

  const int t = threadIdx.x;
  const int w = t >> 6, lane = t & 63, lr = lane & 15, lq = lane >> 4;
  // XCD swizzle: all 64 tiles of a (b,h) on one XCD.
  const int obid = blockIdx.x;
  const int bid = ((obid & 7) << 8) | (obid >> 3);
  const int z  = bid >> 6;
  const int i0 = (bid & 63) << 5;
  const int b = z >> 4, h = z & 15;
  const bool early = (i0 <= 1023);
  const int astart = early ? i0 + 1 : i0;   // 32 MFMA x-rows [astart, astart+32)
  const int grow = early ? 0 : 31;          // boundary strip row
  const int c0   = early ? 0 : i0 + 33;     // boundary col range start

  // B-frags: q rows i0+rg*16+lr, qrr rows astart+rg*16+lr
  bf16x8 fq[2][2], fr[2][2];
#pragma unroll
  for (int rg2 = 0; rg2 < 2; rg2++) {
    const __bf16* qp = qb + (((long)z * 2048 + i0 + rg2 * 16 + lr) << 6) + lq * 8;
    fq[rg2][0] = *(const bf16x8*)qp; fq[rg2][1] = *(const bf16x8*)(qp + 32);
    const __bf16* rp = qrr + (((long)z * 2048 + astart + rg2 * 16 + lr) << 6) + lq * 8;
    fr[rg2][0] = *(const bf16x8*)rp; fr[rg2][1] = *(const bf16x8*)(rp + 32);
  }

  const __bf16* kbz = kb + (((long)z * 2048) << 6);
  const __bf16* rbh = rb + (((long)h * 2048) << 6);
  const float* cbz = cb + (long)z * 2048;
  const _Float16* vtz = vt + (((long)z) << 6) * 2048;

  // ---- boundary row, once per block, coalesced: 8 lanes per column --------
  {
    const int ga    = early ? i0 : i0 + 32;
    const int m0g   = early ? (2047 - i0) : 0;
    int ncols = early ? (i0 + 1) : (2015 - i0);
    if (ncols < 0) ncols = 0;
    const int dl = (t & 7) << 3;          // 8 d's per lane
    bf16x8 qv = *(const bf16x8*)(qrr + (((long)z * 2048 + ga) << 6) + dl);
    for (int c = t >> 3; c < ncols; c += 32) {
      bf16x8 rv = *(const bf16x8*)(rbh + ((long)(m0g + c) << 6) + dl);
      float s = 0.f;
#pragma unroll
      for (int e = 0; e < 8; e++) s += (float)qv[e] * (float)rv[e];
      s += __shfl_xor(s, 1, 64);
      s += __shfl_xor(s, 2, 64);
      s += __shfl_xor(s, 4, 64);
      if ((t & 7) == 0) xB[c] = (_Float16)(s * 0.125f);
    }
  }

  const int rg = w >> 1, sl = w & 1;        // quadrant: row-group, k-slice
  const int row = rg * 16 + lr;             // this lane's q-row (local)
  const int iA = i0 + row;                  // global q-row

  floatx4 oacc[4];
#pragma unroll
  for (int s = 0; s < 4; s++) oacc[s] = floatx4{0.f, 0.f, 0.f, 0.f};
  float psum = 0.f;

  __syncthreads();   // xB visible to all waves

  for (int kp = 0; kp < 16; kp++) {
    const int J0 = kp << 7;
    char* bufb = smem + (kp & 1) * SM_BUF;
    _Float16* qkS = (_Float16*)bufb;
    _Float16* xS  = (_Float16*)(bufb + SM_ONE);

    // qk MFMA (+cb fold): 8 j-tiles, wave does 2. D: row=key-local, col=q-row.
#pragma unroll
    for (int s = 0; s < 2; s++) {
      const int jt = ((w << 1) + s) << 4;     // 0..112
      const __bf16* ap = kbz + ((long)(J0 + jt + lr) << 6) + lq * 8;
      bf16x8 a0 = *(const bf16x8*)ap, a1 = *(const bf16x8*)(ap + 32);
      floatx4 cbv = *(const floatx4*)(cbz + J0 + jt + lq * 4);
      floatx4 c0v{0.f, 0.f, 0.f, 0.f}, c1v{0.f, 0.f, 0.f, 0.f};
      c0v = __builtin_amdgcn_mfma_f32_16x16x32_bf16(a0, fq[0][0], c0v, 0, 0, 0);
      c0v = __builtin_amdgcn_mfma_f32_16x16x32_bf16(a1, fq[0][1], c0v, 0, 0, 0);
      c1v = __builtin_amdgcn_mfma_f32_16x16x32_bf16(a0, fq[1][0], c1v, 0, 0, 0);
      c1v = __builtin_amdgcn_mfma_f32_16x16x32_bf16(a1, fq[1][1], c1v, 0, 0, 0);
      f16x4 s0v, s1v;
#pragma unroll
      for (int g = 0; g < 4; g++) {
        s0v[g] = (_Float16)(c0v[g] * 0.125f + cbv[g]);
        s1v[g] = (_Float16)(c1v[g] * 0.125f + cbv[g]);
      }
      *(f16x4*)&qkS[lr * QSTR3 + jt + lq * 4] = s0v;
      *(f16x4*)&qkS[(16 + lr) * QSTR3 + jt + lq * 4] = s1v;
    }

    // x MFMA: m-window <=11 tiles over 4 waves; wave-uniform predicate.
    const int mb = ((J0 - astart - 32) & 2047) & ~15;
#pragma unroll
    for (int s = 0; s < 3; s++) {
      const int mt = w + (s << 2);
      if (mt < 11) {
        const int m0 = (mb + (mt << 4)) & 2047;
        const __bf16* rp2 = rbh + ((long)(m0 + lr) << 6) + lq * 8;
        bf16x8 r0 = *(const bf16x8*)rp2, r1 = *(const bf16x8*)(rp2 + 32);
        floatx4 x0{0.f, 0.f, 0.f, 0.f}, x1{0.f, 0.f, 0.f, 0.f};
        x0 = __builtin_amdgcn_mfma_f32_16x16x32_bf16(r0, fr[0][0], x0, 0, 0, 0);
        x0 = __builtin_amdgcn_mfma_f32_16x16x32_bf16(r1, fr[0][1], x0, 0, 0, 0);
        x1 = __builtin_amdgcn_mfma_f32_16x16x32_bf16(r0, fr[1][0], x1, 0, 0, 0);
        x1 = __builtin_amdgcn_mfma_f32_16x16x32_bf16(r1, fr[1][1], x1, 0, 0, 0);
#pragma unroll
        for (int rg2 = 0; rg2 < 2; rg2++) {
          const int a = astart + (rg2 << 4) + lr;
          const floatx4 ax = rg2 ? x1 : x0;
#pragma unroll
          for (int g = 0; g < 4; g++) {
            const int m = m0 + (lq << 2) + g;
            const int sum = m + a + 1;
            const int j = sum & 2047;
            const int ri = (sum >= 2048) ? (a - i0) : (a - i0 - 1);
            const int jl = j - J0;
            if ((unsigned)ri < 32u && (unsigned)jl < (unsigned)QW)
              xS[ri * QSTR3 + jl] = (_Float16)(ax[g] * 0.125f);
          }
        }
      }
    }

    // boundary slice: copy this pass's cols from xB (LDS->LDS)
    if (t < QW) {
      const int j = J0 + t;
      const bool act = early ? (j <= i0) : (j >= c0);
      if (act) xS[grow * QSTR3 + t] = xB[j - c0];
    }
    __syncthreads();   // strips of THIS buffer complete

    // V prefetch for own k-slice (in flight under exp)
    f16x8 vf[8];
#pragma unroll
    for (int ks = 0; ks < 2; ks++)
#pragma unroll
      for (int sub = 0; sub < 4; sub++)
        vf[ks * 4 + sub] = *(const f16x8*)(vtz + (long)(sub * 16 + lr) * 2048 +
                                           J0 + sl * 64 + ks * 32 + lq * 8);

    // exp in-register on own quadrant: lane's outputs ARE its PV A-frags.
    f16x8 af[2];
#pragma unroll
    for (int half = 0; half < 2; half++) {
      const int jl = sl * 64 + half * 32 + lq * 8;
      f16x8 hv = *(const f16x8*)(qkS + row * QSTR3 + jl);
      f16x8 xv = *(const f16x8*)(xS + row * QSTR3 + jl);
      f16x8 pr;
#pragma unroll
      for (int e = 0; e < 8; e++) {
        const int jg = J0 + jl + e;
        const float xf = (jg == iA + 1) ? 0.f : (float)xv[e];
        const float ev = __expf((float)hv[e] + xf);
        psum += ev;
        pr[e] = (_Float16)ev;
      }
      af[half] = pr;
    }

    // PV: own quadrant, V already in registers. No trailing barrier:
    // next pass writes the OTHER buffer.
#pragma unroll
    for (int half = 0; half < 2; half++)
#pragma unroll
      for (int sub = 0; sub < 4; sub++)
        oacc[sub] = __builtin_amdgcn_mfma_f32_16x16x32_f16(af[half], vf[half * 4 + sub],
                                                           oacc[sub], 0, 0, 0);
  }
  __syncthreads();   // all PV reads done before overlay

  // fp32 partials overlay buffer 0 (16 KB fits in SM_BUF)
  {
    float* sPart = (float*)smem;   // [2*rg+sl][16][64]
#pragma unroll
    for (int sub = 0; sub < 4; sub++)
#pragma unroll
      for (int g = 0; g < 4; g++)
        sPart[((rg << 1) + sl) * 1024 + ((lq << 2) + g) * 64 + sub * 16 + lr] = oacc[sub][g];
  }
  // row-sum partials: reduce across lq groups (lanes sharing lr)
  psum += __shfl_xor(psum, 16, 64);
  psum += __shfl_xor(psum, 32, 64);
  if (lane < 16) sPs[rg * 16 + lane][sl] = psum;
  __syncthreads();   // partials + sPs complete

  // final: 256 threads x 8 outputs (32 rows x 64 d)
  {
    const float* sPart = (const float*)smem;
    const int r = t >> 3, d0 = (t & 7) << 3;
    const int rg2 = r >> 4, rl = r & 15;
    const float inv = 1.0f / (sPs[r][0] + sPs[r][1]);
    bf16x8 ov;
#pragma unroll
    for (int e = 0; e < 8; e++) {
      float acc = sPart[(rg2 << 1) * 1024 + rl * 64 + d0 + e] +
                  sPart[((rg2 << 1) + 1) * 1024 + rl * 64 + d0 + e];
      ov[e] = (__bf16)(acc * inv);
    }
    *(bf16x8*)&attnb[((long)b * 2048 + i0 + r) * 1024 + h * 64 + d0] = ov;
  }
}

extern "C" void kernel_launch(void* const* d_in, const int* in_sizes, int n_in,
                              void* d_out, int out_size, void* d_ws, size_t ws_size,
                              hipStream_t stream) {
  (void)in_sizes; (void)n_in; (void)out_size; (void)ws_size;
  const float* inputs_kv = (const float*)d_in[0];
  const float* inputs_q  = (const float*)d_in[1];
  const float* pos_embed = (const float*)d_in[2];
  const float* Wq_w = (const float*)d_in[3];
  const float* Wq_b = (const float*)d_in[4];
  const float* Wk_w = (const float*)d_in[5];
  const float* Wk_b = (const float*)d_in[6];
  const float* Wv_w = (const float*)d_in[7];
  const float* Wv_b = (const float*)d_in[8];
  const float* Wr_w = (const float*)d_in[9];
  const float* rwb  = (const float*)d_in[10];
  const float* rrb  = (const float*)d_in[11];
  const float* Wo_w = (const float*)d_in[12];
  const float* Wo_b = (const float*)d_in[13];

  char* ws = (char*)d_ws;
  const long MB = 1 << 20;
  __bf16* Wtq = (__bf16*)(ws + 0 * MB);
  __bf16* Wtk = (__bf16*)(ws + 2 * MB);
  __bf16* Wtv = (__bf16*)(ws + 4 * MB);
  __bf16* Wtr = (__bf16*)(ws + 6 * MB);
  __bf16* Wto = (__bf16*)(ws + 8 * MB);
  __bf16* qb  = (__bf16*)(ws + 10 * MB);
  __bf16* qrr = (__bf16*)(ws + 18 * MB);
  __bf16* kb  = (__bf16*)(ws + 26 * MB);
  _Float16* vt = (_Float16*)(ws + 34 * MB);
  __bf16* rb  = (__bf16*)(ws + 42 * MB);
  float*  cb  = (float*)(ws + 46 * MB);               // 256 KB
  __bf16* attnb = (__bf16*)(ws + 47 * MB);            // 8 MB bf16 attention out

  dim3 blk(256);

  TRP tp{};
  tp.src[0] = Wq_w; tp.dst[0] = Wtq;
  tp.src[1] = Wk_w; tp.dst[1] = Wtk;
  tp.src[2] = Wv_w; tp.dst[2] = Wtv;
  tp.src[3] = Wr_w; tp.dst[3] = Wtr;
  tp.src[4] = Wo_w; tp.dst[4] = Wto;
  tr_cvt_all<<<dim3(1280), blk, 0, stream>>>(tp);

  QPAll q{};
  q.qin = inputs_q; q.kvin = inputs_kv; q.pos = pos_embed;
  q.Wtq = Wtq; q.Wtk = Wtk; q.Wtv = Wtv; q.Wtr = Wtr;
  q.bq = Wq_b; q.bk = Wk_b; q.bv = Wv_b; q.rrb = rrb;
  q.qb = qb; q.qrr = qrr; q.kb = kb; q.rb = rb; q.vt = vt;
  qkvr_k<<<dim3(896), blk, 0, stream>>>(q);

  cb_k<<<dim3(256), blk, 0, stream>>>(kb, rwb, cb);

  fused_k<<<dim3(2048), dim3(256), FUSED_SMEM, stream>>>(qb, qrr, kb, vt, rb, cb, attnb);

  // Output projection: d_out = attn(bf16) @ Wo + bo
  GP o{};
  o.A = attnb; o.B = Wto; o.lda = 1024; o.ldb = 1024; o.K = 1024;
  o.bias = Wo_b; o.outF = (float*)d_out;
  gemm_o<<<dim3(8, 32), blk, 0, stream>>>(o);
}

// Round 7
// 516.985 us; speedup vs baseline: 1.1003x; 1.1003x over previous
//
#include <hip/hip_runtime.h>

// RelMultiHeadAttention (Transformer-XL) on gfx950.
// B=2, S=2048, D=1024, H=16, hd=64.
// R13: R10 base (best measured: 309us fused, LDS p~ exp, 3 barriers/pass)
// with the j-pass WIDENED 128->256 cols. Mechanism: R10 is latency-bound
// (all pipes <46%, ~70% stall); each phase is shorter than one L2 round
// trip so every phase eats its own latency, 48 barrier convoys re-expose
// it. Widening doubles independent work per phase (16 qk tiles, 19 x tiles,
// 32-elem exp, 16 PV MFMAs per wave) and halves convoys (48->24). No new
// live arrays (V loads stay inline) -> no R11/R12 codegen regression.
// LDS 35.8KB -> 4 blocks/CU (= measured residency anyway).

typedef float  floatx4 __attribute__((ext_vector_type(4)));
typedef __bf16 bf16x8  __attribute__((ext_vector_type(8)));
typedef _Float16 f16x8 __attribute__((ext_vector_type(8)));
typedef _Float16 f16x4 __attribute__((ext_vector_type(4)));

#define LSTR 40   // proj-GEMM LDS row stride (bf16): conflict-free b128

struct GP {
  const void* A;
  const __bf16* B;
  int lda, ldb, K;
  float* outF;
  __bf16* out1;
  const float* bias;
};

// Output projection only (attn bf16 @ Wo + bo -> f32)
__global__ void __launch_bounds__(256) gemm_o(GP p) {
  __shared__ __bf16 lA[128 * LSTR];
  __shared__ __bf16 lB[128 * LSTR];
  const int t = threadIdx.x;
  const int wave = t >> 6, lane = t & 63;
  const int m0 = blockIdx.y * 128, n0 = blockIdx.x * 128;
  const int srow = t >> 2, scol = (t & 3) << 3;
  const __bf16* Ab = (const __bf16*)p.A;
  const __bf16* Bb = p.B;

  floatx4 acc[4][4];
#pragma unroll
  for (int i = 0; i < 4; i++)
#pragma unroll
    for (int j = 0; j < 4; j++) acc[i][j] = floatx4{0.f, 0.f, 0.f, 0.f};

  const int lr = lane & 15, lq = lane >> 4;
  const int wr = (wave >> 1) << 6, wc = (wave & 1) << 6;

  for (int kk = 0; kk < p.K; kk += 32) {
#pragma unroll
    for (int h2 = 0; h2 < 2; h2++) {
      int r = srow + (h2 << 6);
      const __bf16* ap = Ab + (long)(m0 + r) * p.lda + kk + scol;
      *(bf16x8*)&lA[r * LSTR + scol] = *(const bf16x8*)ap;
      const __bf16* bp = Bb + (long)(n0 + r) * p.ldb + kk + scol;
      *(bf16x8*)&lB[r * LSTR + scol] = *(const bf16x8*)bp;
    }
    __syncthreads();
    bf16x8 aF[4], bF[4];
#pragma unroll
    for (int i = 0; i < 4; i++)
      aF[i] = *(bf16x8*)&lA[(wr + i * 16 + lr) * LSTR + (lq << 3)];
#pragma unroll
    for (int i = 0; i < 4; i++)
      bF[i] = *(bf16x8*)&lB[(wc + i * 16 + lr) * LSTR + (lq << 3)];
#pragma unroll
    for (int i = 0; i < 4; i++)
#pragma unroll
      for (int j = 0; j < 4; j++)
        acc[i][j] = __builtin_amdgcn_mfma_f32_16x16x32_bf16(aF[i], bF[j], acc[i][j], 0, 0, 0);
    __syncthreads();
  }
#pragma unroll
  for (int i = 0; i < 4; i++)
#pragma unroll
    for (int j = 0; j < 4; j++) {
      int col = n0 + wc + j * 16 + lr;
#pragma unroll
      for (int g = 0; g < 4; g++) {
        int rl = m0 + wr + i * 16 + (lq << 2) + g;
        p.outF[(long)rl * 1024 + col] = acc[i][j][g] + p.bias[col];
      }
    }
}

// ---- merged Q/K/V/R projection: one launch, job table ----------------------
struct QPAll {
  const float *qin, *kvin, *pos;
  const __bf16 *Wtq, *Wtk, *Wtv, *Wtr;
  const float *bq, *bk, *bv, *rrb;
  __bf16 *qb, *qrr, *kb, *rb;
  _Float16 *vt;
};

__global__ void __launch_bounds__(256, 3) qkvr_k(QPAll p) {
  __shared__ __bf16 lA[128 * LSTR];
  __shared__ __bf16 lB[128 * LSTR];
  const int jb = blockIdx.x;
  const int job = (jb >= 768) ? 3 : (jb >> 8);
  const int local = jb - ((job == 3) ? 768 : (job << 8));
  const int m0 = (local >> 3) * 128, n0 = (local & 7) * 128;

  const float* A; const __bf16* B; const float* bias;
  if (job == 0)      { A = p.qin;  B = p.Wtq; bias = p.bq; }
  else if (job == 1) { A = p.kvin; B = p.Wtk; bias = p.bk; }
  else if (job == 2) { A = p.kvin; B = p.Wtv; bias = p.bv; }
  else               { A = p.pos;  B = p.Wtr; bias = nullptr; }

  const int t = threadIdx.x;
  const int wave = t >> 6, lane = t & 63;
  const int srow = t >> 2, scol = (t & 3) << 3;

  floatx4 acc[4][4];
#pragma unroll
  for (int i = 0; i < 4; i++)
#pragma unroll
    for (int j = 0; j < 4; j++) acc[i][j] = floatx4{0.f, 0.f, 0.f, 0.f};

  const int lr = lane & 15, lq = lane >> 4;
  const int wr = (wave >> 1) << 6, wc = (wave & 1) << 6;

  for (int kk = 0; kk < 1024; kk += 32) {
#pragma unroll
    for (int h2 = 0; h2 < 2; h2++) {
      int r = srow + (h2 << 6);
      const float* ap = A + (long)(m0 + r) * 1024 + kk + scol;
      float4 f0 = *(const float4*)ap;
      float4 f1 = *(const float4*)(ap + 4);
      bf16x8 o;
      o[0] = (__bf16)f0.x; o[1] = (__bf16)f0.y; o[2] = (__bf16)f0.z; o[3] = (__bf16)f0.w;
      o[4] = (__bf16)f1.x; o[5] = (__bf16)f1.y; o[6] = (__bf16)f1.z; o[7] = (__bf16)f1.w;
      *(bf16x8*)&lA[r * LSTR + scol] = o;
      const __bf16* bp = B + (long)(n0 + r) * 1024 + kk + scol;
      *(bf16x8*)&lB[r * LSTR + scol] = *(const bf16x8*)bp;
    }
    __syncthreads();
    bf16x8 aF[4], bF[4];
#pragma unroll
    for (int i = 0; i < 4; i++)
      aF[i] = *(bf16x8*)&lA[(wr + i * 16 + lr) * LSTR + (lq << 3)];
#pragma unroll
    for (int i = 0; i < 4; i++)
      bF[i] = *(bf16x8*)&lB[(wc + i * 16 + lr) * LSTR + (lq << 3)];
#pragma unroll
    for (int i = 0; i < 4; i++)
#pragma unroll
      for (int j = 0; j < 4; j++)
        acc[i][j] = __builtin_amdgcn_mfma_f32_16x16x32_bf16(aF[i], bF[j], acc[i][j], 0, 0, 0);
    __syncthreads();
  }

  // epilogue per job; C/D: col=lane&15, row=(lane>>4)*4+reg
#pragma unroll
  for (int i = 0; i < 4; i++)
#pragma unroll
    for (int j = 0; j < 4; j++) {
      int col = n0 + wc + j * 16 + lr;
#pragma unroll
      for (int g = 0; g < 4; g++) {
        int rl = m0 + wr + i * 16 + (lq << 2) + g;
        float val = acc[i][j][g];
        int hh = col >> 6, d = col & 63;
        if (job == 3) {
          long dst = (((long)hh * 2048 + rl) << 6) + d;
          p.rb[dst] = (__bf16)val;
        } else {
          int bb = rl >> 11, s = rl & 2047;
          float v = val + bias[col];
          if (job == 0) {
            long dst = (((long)(bb * 16 + hh) * 2048 + s) << 6) + d;
            p.qb[dst] = (__bf16)v;
            p.qrr[dst] = (__bf16)(v + p.rrb[col]);
          } else if (job == 1) {
            long dst = (((long)(bb * 16 + hh) * 2048 + s) << 6) + d;
            p.kb[dst] = (__bf16)v;
          } else {
            long dst = ((((long)(bb * 16 + hh)) << 6) + d) * 2048 + s;
            p.vt[dst] = (_Float16)v;
          }
        }
      }
    }
}

__global__ void __launch_bounds__(256) cb_k(const __bf16* kb, const float* rwb, float* cb) {
  long id = (long)blockIdx.x * 256 + threadIdx.x;  // 32*2048
  int z = (int)(id >> 11);
  int j = (int)(id & 2047);
  int h = z & 15;
  const __bf16* kp = kb + (((long)z * 2048 + j) << 6);
  float s = 0.f;
#pragma unroll
  for (int c = 0; c < 8; c++) {
    bf16x8 kv = *(const bf16x8*)(kp + c * 8);
#pragma unroll
    for (int e = 0; e < 8; e++) s += rwb[h * 64 + c * 8 + e] * (float)kv[e];
  }
  cb[id] = s * 0.125f;
}

// All five weight transposes in one launch: 5 x 256 tiles.
struct TRP { const float* src[5]; __bf16* dst[5]; };
__global__ void __launch_bounds__(256) tr_cvt_all(TRP p) {
  __shared__ float tile[64][65];
  const int id = blockIdx.x;
  const int which = id >> 8;
  const int local = id & 255;
  const int bx = local & 15, by = local >> 4;
  const float* src = p.src[which];
  __bf16* dst = p.dst[which];
  int tx = threadIdx.x & 63, ty = threadIdx.x >> 6;
#pragma unroll
  for (int r = ty; r < 64; r += 4)
    tile[r][tx] = src[(long)(by * 64 + r) * 1024 + bx * 64 + tx];
  __syncthreads();
#pragma unroll
  for (int r = ty; r < 64; r += 4)
    dst[(long)(bx * 64 + r) * 1024 + by * 64 + tx] = (__bf16)tile[tx][r];
}

// -------- fused scores + rel-shift + softmax + PV: 4-wave blocks -----------
// 32 q-rows/block, 8 j-passes of width 256. Strips [32][QSTR3] f16 (qk, x)
// + xB[1024] f16. Per pass: qk+x MFMA + boundary copy -> barrier A -> exp
// in place -> barrier B -> PV (inline V loads) -> barrier C.
#define QW 256
#define QSTR3 264                         // row stride f16 (256+8)
#define SM_ONE (32 * QSTR3 * 2)           // 16896 B per strip
#define FUSED_SMEM (2 * SM_ONE + 2048)    // 35840 B -> 4 blocks/CU

__global__ void __launch_bounds__(256, 4) fused_k(const __bf16* __restrict__ qb,
                                                  const __bf16* __restrict__ qrr,
                                                  const __bf16* __restrict__ kb,
                                                  const _Float16* __restrict__ vt,
                                                  const __bf16* __restrict__ rb,
                                                  const float* __restrict__ cb,
                                                  __bf16* __restrict__ attnb) {
  extern __shared__ char smem[];
  _Float16* qkS = (_Float16*)smem;              // [32][QSTR3]
  _Float16* xS  = (_Float16*)(smem + SM_ONE);   // [32][QSTR3]
  _Float16* xB  = (_Float16*)(smem + 2 * SM_ONE);  // [1024] boundary row
  __shared__ float sInv[32];

  const int t = threadIdx.x;
  const int w = t >> 6, lane = t & 63, lr = lane & 15, lq = lane >> 4;
  // XCD swizzle: all 64 tiles of a (b,h) on one XCD.
  const int obid = blockIdx.x;
  const int bid = ((obid & 7) << 8) | (obid >> 3);
  const int z  = bid >> 6;
  const int i0 = (bid & 63) << 5;
  const int b = z >> 4, h = z & 15;
  const bool early = (i0 <= 1023);
  const int astart = early ? i0 + 1 : i0;   // 32 MFMA x-rows [astart, astart+32)
  const int grow = early ? 0 : 31;          // boundary strip row
  const int c0   = early ? 0 : i0 + 33;     // boundary col range start

  // B-frags: q rows i0+rg*16+lr, qrr rows astart+rg*16+lr
  bf16x8 fq[2][2], fr[2][2];
#pragma unroll
  for (int rg2 = 0; rg2 < 2; rg2++) {
    const __bf16* qp = qb + (((long)z * 2048 + i0 + rg2 * 16 + lr) << 6) + lq * 8;
    fq[rg2][0] = *(const bf16x8*)qp; fq[rg2][1] = *(const bf16x8*)(qp + 32);
    const __bf16* rp = qrr + (((long)z * 2048 + astart + rg2 * 16 + lr) << 6) + lq * 8;
    fr[rg2][0] = *(const bf16x8*)rp; fr[rg2][1] = *(const bf16x8*)(rp + 32);
  }

  const __bf16* kbz = kb + (((long)z * 2048) << 6);
  const __bf16* rbh = rb + (((long)h * 2048) << 6);
  const float* cbz = cb + (long)z * 2048;
  const _Float16* vtz = vt + (((long)z) << 6) * 2048;

  // ---- boundary row, once per block, coalesced: 8 lanes per column --------
  {
    const int ga    = early ? i0 : i0 + 32;
    const int m0g   = early ? (2047 - i0) : 0;
    int ncols = early ? (i0 + 1) : (2015 - i0);
    if (ncols < 0) ncols = 0;
    const int dl = (t & 7) << 3;          // 8 d's per lane
    bf16x8 qv = *(const bf16x8*)(qrr + (((long)z * 2048 + ga) << 6) + dl);
    for (int c = t >> 3; c < ncols; c += 32) {
      bf16x8 rv = *(const bf16x8*)(rbh + ((long)(m0g + c) << 6) + dl);
      float s = 0.f;
#pragma unroll
      for (int e = 0; e < 8; e++) s += (float)qv[e] * (float)rv[e];
      s += __shfl_xor(s, 1, 64);
      s += __shfl_xor(s, 2, 64);
      s += __shfl_xor(s, 4, 64);
      if ((t & 7) == 0) xB[c] = (_Float16)(s * 0.125f);
    }
  }
  __syncthreads();   // xB visible to all waves

  const int erow = w * 8 + (lane >> 3);     // exp row for this lane
  const int ecol = (lane & 7) * 16;         // exp col base within half-pass
  const int rg = w >> 1, sl = w & 1;        // PV role: row-group, k-slice

  floatx4 oacc[4];
#pragma unroll
  for (int s = 0; s < 4; s++) oacc[s] = floatx4{0.f, 0.f, 0.f, 0.f};
  float psum = 0.f;

  for (int kp = 0; kp < 8; kp++) {
    const int J0 = kp << 8;

    // qk MFMA (+cb fold): 16 j-tiles, wave does 4. D: row=key-local, col=q-row.
#pragma unroll
    for (int s = 0; s < 4; s++) {
      const int jt = ((w << 2) + s) << 4;     // 0..240
      const __bf16* ap = kbz + ((long)(J0 + jt + lr) << 6) + lq * 8;
      bf16x8 a0 = *(const bf16x8*)ap, a1 = *(const bf16x8*)(ap + 32);
      floatx4 cbv = *(const floatx4*)(cbz + J0 + jt + lq * 4);
      floatx4 c0v{0.f, 0.f, 0.f, 0.f}, c1v{0.f, 0.f, 0.f, 0.f};
      c0v = __builtin_amdgcn_mfma_f32_16x16x32_bf16(a0, fq[0][0], c0v, 0, 0, 0);
      c0v = __builtin_amdgcn_mfma_f32_16x16x32_bf16(a1, fq[0][1], c0v, 0, 0, 0);
      c1v = __builtin_amdgcn_mfma_f32_16x16x32_bf16(a0, fq[1][0], c1v, 0, 0, 0);
      c1v = __builtin_amdgcn_mfma_f32_16x16x32_bf16(a1, fq[1][1], c1v, 0, 0, 0);
      f16x4 s0v, s1v;
#pragma unroll
      for (int g = 0; g < 4; g++) {
        s0v[g] = (_Float16)(c0v[g] * 0.125f + cbv[g]);
        s1v[g] = (_Float16)(c1v[g] * 0.125f + cbv[g]);
      }
      *(f16x4*)&qkS[lr * QSTR3 + jt + lq * 4] = s0v;
      *(f16x4*)&qkS[(16 + lr) * QSTR3 + jt + lq * 4] = s1v;
    }

    // x MFMA: m-window = 287 consecutive values -> <=19 tiles over 4 waves;
    // wave-uniform predicate. Scatter with shift pre-applied.
    const int mb = ((J0 - astart - 32) & 2047) & ~15;
#pragma unroll
    for (int s = 0; s < 5; s++) {
      const int mt = w + (s << 2);
      if (mt < 19) {
        const int m0 = (mb + (mt << 4)) & 2047;
        const __bf16* rp2 = rbh + ((long)(m0 + lr) << 6) + lq * 8;
        bf16x8 r0 = *(const bf16x8*)rp2, r1 = *(const bf16x8*)(rp2 + 32);
        floatx4 x0{0.f, 0.f, 0.f, 0.f}, x1{0.f, 0.f, 0.f, 0.f};
        x0 = __builtin_amdgcn_mfma_f32_16x16x32_bf16(r0, fr[0][0], x0, 0, 0, 0);
        x0 = __builtin_amdgcn_mfma_f32_16x16x32_bf16(r1, fr[0][1], x0, 0, 0, 0);
        x1 = __builtin_amdgcn_mfma_f32_16x16x32_bf16(r0, fr[1][0], x1, 0, 0, 0);
        x1 = __builtin_amdgcn_mfma_f32_16x16x32_bf16(r1, fr[1][1], x1, 0, 0, 0);
#pragma unroll
        for (int rg2 = 0; rg2 < 2; rg2++) {
          const int a = astart + (rg2 << 4) + lr;
          const floatx4 ax = rg2 ? x1 : x0;
#pragma unroll
          for (int g = 0; g < 4; g++) {
            const int m = m0 + (lq << 2) + g;
            const int sum = m + a + 1;
            const int j = sum & 2047;
            const int ri = (sum >= 2048) ? (a - i0) : (a - i0 - 1);
            const int jl = j - J0;
            if ((unsigned)ri < 32u && (unsigned)jl < (unsigned)QW)
              xS[ri * QSTR3 + jl] = (_Float16)(ax[g] * 0.125f);
          }
        }
      }
    }

    // boundary slice: each thread copies 1 col of this pass from xB
    {
      const int j = J0 + t;
      const bool act = early ? (j <= i0) : (j >= c0);
      if (act) xS[grow * QSTR3 + t] = xB[j - c0];
    }
    __syncthreads();   // A: strips complete

    // exp in place: row erow, 2 x 16 cols (halves 128 apart); zero at j==i+1.
    {
      const int iA = i0 + erow;
      _Float16* qrow = qkS + erow * QSTR3;
      const _Float16* xrow = xS + erow * QSTR3;
#pragma unroll
      for (int ii = 0; ii < 2; ii++) {
        const int cbase = ii * 128 + ecol;
        f16x8 h0 = *(const f16x8*)(qrow + cbase), h1 = *(const f16x8*)(qrow + cbase + 8);
        f16x8 v0 = *(const f16x8*)(xrow + cbase), v1 = *(const f16x8*)(xrow + cbase + 8);
        f16x8 p0, p1;
#pragma unroll
        for (int e = 0; e < 8; e++) {
          const int jg = J0 + cbase + e;
          float xf = (jg == iA + 1) ? 0.f : (float)v0[e];
          float ev = __expf((float)h0[e] + xf);
          psum += ev; p0[e] = (_Float16)ev;
          const int jg1 = jg + 8;
          float xf1 = (jg1 == iA + 1) ? 0.f : (float)v1[e];
          float ev1 = __expf((float)h1[e] + xf1);
          psum += ev1; p1[e] = (_Float16)ev1;
        }
        *(f16x8*)(qrow + cbase) = p0;
        *(f16x8*)(qrow + cbase + 8) = p1;
      }
    }
    __syncthreads();   // B: p~ complete

    // PV: wave (rg, sl) contracts keys [J0+sl*128, +128) for rows rg*16..+16
#pragma unroll
    for (int ch = 0; ch < 4; ch++) {
      const int kk = sl * 128 + ch * 32;
      f16x8 af = *(const f16x8*)(qkS + (rg * 16 + lr) * QSTR3 + kk + lq * 8);
#pragma unroll
      for (int sub = 0; sub < 4; sub++) {
        f16x8 bfv = *(const f16x8*)(vtz + (long)(sub * 16 + lr) * 2048 + J0 + kk + lq * 8);
        oacc[sub] = __builtin_amdgcn_mfma_f32_16x16x32_f16(af, bfv, oacc[sub], 0, 0, 0);
      }
    }
    __syncthreads();   // C: strip reads done before next pass overwrites
  }

  // fp32 partials overlay the strips (dead after barrier C of last pass)
  {
    float* sPart = (float*)smem;   // [2*rg+sl][16][64]
#pragma unroll
    for (int sub = 0; sub < 4; sub++)
#pragma unroll
      for (int g = 0; g < 4; g++)
        sPart[((rg << 1) + sl) * 1024 + ((lq << 2) + g) * 64 + sub * 16 + lr] = oacc[sub][g];
  }
  // row sums: reduce 8 col-lanes of each row
#pragma unroll
  for (int o = 1; o < 8; o <<= 1) psum += __shfl_xor(psum, o, 64);
  if ((lane & 7) == 0) sInv[erow] = 1.0f / psum;
  __syncthreads();   // D: partials + sInv complete

  // final: 256 threads x 8 outputs (32 rows x 64 d)
  {
    const float* sPart = (const float*)smem;
    const int r = t >> 3, d0 = (t & 7) << 3;
    const int rg2 = r >> 4, rl = r & 15;
    const float inv = sInv[r];
    bf16x8 ov;
#pragma unroll
    for (int e = 0; e < 8; e++) {
      float acc = sPart[(rg2 << 1) * 1024 + rl * 64 + d0 + e] +
                  sPart[((rg2 << 1) + 1) * 1024 + rl * 64 + d0 + e];
      ov[e] = (__bf16)(acc * inv);
    }
    *(bf16x8*)&attnb[((long)b * 2048 + i0 + r) * 1024 + h * 64 + d0] = ov;
  }
}

extern "C" void kernel_launch(void* const* d_in, const int* in_sizes, int n_in,
                              void* d_out, int out_size, void* d_ws, size_t ws_size,
                              hipStream_t stream) {
  (void)in_sizes; (void)n_in; (void)out_size; (void)ws_size;
  const float* inputs_kv = (const float*)d_in[0];
  const float* inputs_q  = (const float*)d_in[1];
  const float* pos_embed = (const float*)d_in[2];
  const float* Wq_w = (const float*)d_in[3];
  const float* Wq_b = (const float*)d_in[4];
  const float* Wk_w = (const float*)d_in[5];
  const float* Wk_b = (const float*)d_in[6];
  const float* Wv_w = (const float*)d_in[7];
  const float* Wv_b = (const float*)d_in[8];
  const float* Wr_w = (const float*)d_in[9];
  const float* rwb  = (const float*)d_in[10];
  const float* rrb  = (const float*)d_in[11];
  const float* Wo_w = (const float*)d_in[12];
  const float* Wo_b = (const float*)d_in[13];

  char* ws = (char*)d_ws;
  const long MB = 1 << 20;
  __bf16* Wtq = (__bf16*)(ws + 0 * MB);
  __bf16* Wtk = (__bf16*)(ws + 2 * MB);
  __bf16* Wtv = (__bf16*)(ws + 4 * MB);
  __bf16* Wtr = (__bf16*)(ws + 6 * MB);
  __bf16* Wto = (__bf16*)(ws + 8 * MB);
  __bf16* qb  = (__bf16*)(ws + 10 * MB);
  __bf16* qrr = (__bf16*)(ws + 18 * MB);
  __bf16* kb  = (__bf16*)(ws + 26 * MB);
  _Float16* vt = (_Float16*)(ws + 34 * MB);
  __bf16* rb  = (__bf16*)(ws + 42 * MB);
  float*  cb  = (float*)(ws + 46 * MB);               // 256 KB
  __bf16* attnb = (__bf16*)(ws + 47 * MB);            // 8 MB bf16 attention out

  dim3 blk(256);

  TRP tp{};
  tp.src[0] = Wq_w; tp.dst[0] = Wtq;
  tp.src[1] = Wk_w; tp.dst[1] = Wtk;
  tp.src[2] = Wv_w; tp.dst[2] = Wtv;
  tp.src[3] = Wr_w; tp.dst[3] = Wtr;
  tp.src[4] = Wo_w; tp.dst[4] = Wto;
  tr_cvt_all<<<dim3(1280), blk, 0, stream>>>(tp);

  QPAll q{};
  q.qin = inputs_q; q.kvin = inputs_kv; q.pos = pos_embed;
  q.Wtq = Wtq; q.Wtk = Wtk; q.Wtv = Wtv; q.Wtr = Wtr;
  q.bq = Wq_b; q.bk = Wk_b; q.bv = Wv_b; q.rrb = rrb;
  q.qb = qb; q.qrr = qrr; q.kb = kb; q.rb = rb; q.vt = vt;
  qkvr_k<<<dim3(896), blk, 0, stream>>>(q);

  cb_k<<<dim3(256), blk, 0, stream>>>(kb, rwb, cb);

  fused_k<<<dim3(2048), dim3(256), FUSED_SMEM, stream>>>(qb, qrr, kb, vt, rb, cb, attnb);

  // Output projection: d_out = attn(bf16) @ Wo + bo
  GP o{};
  o.A = attnb; o.B = Wto; o.lda = 1024; o.ldb = 1024; o.K = 1024;
  o.bias = Wo_b; o.outF = (float*)d_out;
  gemm_o<<<dim3(8, 32), blk, 0, stream>>>(o);
}

// Round 8
// 507.597 us; speedup vs baseline: 1.1207x; 1.0185x over previous
//
#include <hip/hip_runtime.h>
#include <hip/hip_fp16.h>

// RelMultiHeadAttention (Transformer-XL) on gfx950.
// B=2, S=2048, D=1024, H=16, hd=64.
// R14: R13 base (256-col passes, 298us fused) + packed-f16 softmax. R13 is
// issue-bound (~2.2k issue-cyc/wave/pass, VALU 41%): exp phase was ~8 scalar
// VALU/element. Now: log2(e) folded into ALL score scales (cb_k, qk store,
// x scatter, xB) so exp==exp2; exp phase = v_pk_add_f16 + v_exp_f16 (h2exp2)
// + v_dot2_f32_f16 row-sum => ~2 inst/element, zero index math. The j==i+1
// hole is PRE-ZEROED in xS (32 one-off b16 writes; provably collision-free)
// so the per-element select disappears. psum sums the stored f16 p~.

typedef float  floatx4 __attribute__((ext_vector_type(4)));
typedef __bf16 bf16x8  __attribute__((ext_vector_type(8)));
typedef _Float16 f16x8 __attribute__((ext_vector_type(8)));
typedef _Float16 f16x4 __attribute__((ext_vector_type(4)));
typedef _Float16 f16x2 __attribute__((ext_vector_type(2)));

#define LSTR 40   // proj-GEMM LDS row stride (bf16): conflict-free b128
#define SCL 0.18033688f   // 0.125 * log2(e): score scale with exp->exp2 fold

struct GP {
  const void* A;
  const __bf16* B;
  int lda, ldb, K;
  float* outF;
  __bf16* out1;
  const float* bias;
};

// Output projection only (attn bf16 @ Wo + bo -> f32)
__global__ void __launch_bounds__(256) gemm_o(GP p) {
  __shared__ __bf16 lA[128 * LSTR];
  __shared__ __bf16 lB[128 * LSTR];
  const int t = threadIdx.x;
  const int wave = t >> 6, lane = t & 63;
  const int m0 = blockIdx.y * 128, n0 = blockIdx.x * 128;
  const int srow = t >> 2, scol = (t & 3) << 3;
  const __bf16* Ab = (const __bf16*)p.A;
  const __bf16* Bb = p.B;

  floatx4 acc[4][4];
#pragma unroll
  for (int i = 0; i < 4; i++)
#pragma unroll
    for (int j = 0; j < 4; j++) acc[i][j] = floatx4{0.f, 0.f, 0.f, 0.f};

  const int lr = lane & 15, lq = lane >> 4;
  const int wr = (wave >> 1) << 6, wc = (wave & 1) << 6;

  for (int kk = 0; kk < p.K; kk += 32) {
#pragma unroll
    for (int h2 = 0; h2 < 2; h2++) {
      int r = srow + (h2 << 6);
      const __bf16* ap = Ab + (long)(m0 + r) * p.lda + kk + scol;
      *(bf16x8*)&lA[r * LSTR + scol] = *(const bf16x8*)ap;
      const __bf16* bp = Bb + (long)(n0 + r) * p.ldb + kk + scol;
      *(bf16x8*)&lB[r * LSTR + scol] = *(const bf16x8*)bp;
    }
    __syncthreads();
    bf16x8 aF[4], bF[4];
#pragma unroll
    for (int i = 0; i < 4; i++)
      aF[i] = *(bf16x8*)&lA[(wr + i * 16 + lr) * LSTR + (lq << 3)];
#pragma unroll
    for (int i = 0; i < 4; i++)
      bF[i] = *(bf16x8*)&lB[(wc + i * 16 + lr) * LSTR + (lq << 3)];
#pragma unroll
    for (int i = 0; i < 4; i++)
#pragma unroll
      for (int j = 0; j < 4; j++)
        acc[i][j] = __builtin_amdgcn_mfma_f32_16x16x32_bf16(aF[i], bF[j], acc[i][j], 0, 0, 0);
    __syncthreads();
  }
#pragma unroll
  for (int i = 0; i < 4; i++)
#pragma unroll
    for (int j = 0; j < 4; j++) {
      int col = n0 + wc + j * 16 + lr;
#pragma unroll
      for (int g = 0; g < 4; g++) {
        int rl = m0 + wr + i * 16 + (lq << 2) + g;
        p.outF[(long)rl * 1024 + col] = acc[i][j][g] + p.bias[col];
      }
    }
}

// ---- merged Q/K/V/R projection: one launch, job table ----------------------
struct QPAll {
  const float *qin, *kvin, *pos;
  const __bf16 *Wtq, *Wtk, *Wtv, *Wtr;
  const float *bq, *bk, *bv, *rrb;
  __bf16 *qb, *qrr, *kb, *rb;
  _Float16 *vt;
};

__global__ void __launch_bounds__(256, 3) qkvr_k(QPAll p) {
  __shared__ __bf16 lA[128 * LSTR];
  __shared__ __bf16 lB[128 * LSTR];
  const int jb = blockIdx.x;
  const int job = (jb >= 768) ? 3 : (jb >> 8);
  const int local = jb - ((job == 3) ? 768 : (job << 8));
  const int m0 = (local >> 3) * 128, n0 = (local & 7) * 128;

  const float* A; const __bf16* B; const float* bias;
  if (job == 0)      { A = p.qin;  B = p.Wtq; bias = p.bq; }
  else if (job == 1) { A = p.kvin; B = p.Wtk; bias = p.bk; }
  else if (job == 2) { A = p.kvin; B = p.Wtv; bias = p.bv; }
  else               { A = p.pos;  B = p.Wtr; bias = nullptr; }

  const int t = threadIdx.x;
  const int wave = t >> 6, lane = t & 63;
  const int srow = t >> 2, scol = (t & 3) << 3;

  floatx4 acc[4][4];
#pragma unroll
  for (int i = 0; i < 4; i++)
#pragma unroll
    for (int j = 0; j < 4; j++) acc[i][j] = floatx4{0.f, 0.f, 0.f, 0.f};

  const int lr = lane & 15, lq = lane >> 4;
  const int wr = (wave >> 1) << 6, wc = (wave & 1) << 6;

  for (int kk = 0; kk < 1024; kk += 32) {
#pragma unroll
    for (int h2 = 0; h2 < 2; h2++) {
      int r = srow + (h2 << 6);
      const float* ap = A + (long)(m0 + r) * 1024 + kk + scol;
      float4 f0 = *(const float4*)ap;
      float4 f1 = *(const float4*)(ap + 4);
      bf16x8 o;
      o[0] = (__bf16)f0.x; o[1] = (__bf16)f0.y; o[2] = (__bf16)f0.z; o[3] = (__bf16)f0.w;
      o[4] = (__bf16)f1.x; o[5] = (__bf16)f1.y; o[6] = (__bf16)f1.z; o[7] = (__bf16)f1.w;
      *(bf16x8*)&lA[r * LSTR + scol] = o;
      const __bf16* bp = B + (long)(n0 + r) * 1024 + kk + scol;
      *(bf16x8*)&lB[r * LSTR + scol] = *(const bf16x8*)bp;
    }
    __syncthreads();
    bf16x8 aF[4], bF[4];
#pragma unroll
    for (int i = 0; i < 4; i++)
      aF[i] = *(bf16x8*)&lA[(wr + i * 16 + lr) * LSTR + (lq << 3)];
#pragma unroll
    for (int i = 0; i < 4; i++)
      bF[i] = *(bf16x8*)&lB[(wc + i * 16 + lr) * LSTR + (lq << 3)];
#pragma unroll
    for (int i = 0; i < 4; i++)
#pragma unroll
      for (int j = 0; j < 4; j++)
        acc[i][j] = __builtin_amdgcn_mfma_f32_16x16x32_bf16(aF[i], bF[j], acc[i][j], 0, 0, 0);
    __syncthreads();
  }

  // epilogue per job; C/D: col=lane&15, row=(lane>>4)*4+reg
#pragma unroll
  for (int i = 0; i < 4; i++)
#pragma unroll
    for (int j = 0; j < 4; j++) {
      int col = n0 + wc + j * 16 + lr;
#pragma unroll
      for (int g = 0; g < 4; g++) {
        int rl = m0 + wr + i * 16 + (lq << 2) + g;
        float val = acc[i][j][g];
        int hh = col >> 6, d = col & 63;
        if (job == 3) {
          long dst = (((long)hh * 2048 + rl) << 6) + d;
          p.rb[dst] = (__bf16)val;
        } else {
          int bb = rl >> 11, s = rl & 2047;
          float v = val + bias[col];
          if (job == 0) {
            long dst = (((long)(bb * 16 + hh) * 2048 + s) << 6) + d;
            p.qb[dst] = (__bf16)v;
            p.qrr[dst] = (__bf16)(v + p.rrb[col]);
          } else if (job == 1) {
            long dst = (((long)(bb * 16 + hh) * 2048 + s) << 6) + d;
            p.kb[dst] = (__bf16)v;
          } else {
            long dst = ((((long)(bb * 16 + hh)) << 6) + d) * 2048 + s;
            p.vt[dst] = (_Float16)v;
          }
        }
      }
    }
}

// cb pre-scaled by 0.125*log2(e) so fused exp2 needs no extra factor.
__global__ void __launch_bounds__(256) cb_k(const __bf16* kb, const float* rwb, float* cb) {
  long id = (long)blockIdx.x * 256 + threadIdx.x;  // 32*2048
  int z = (int)(id >> 11);
  int j = (int)(id & 2047);
  int h = z & 15;
  const __bf16* kp = kb + (((long)z * 2048 + j) << 6);
  float s = 0.f;
#pragma unroll
  for (int c = 0; c < 8; c++) {
    bf16x8 kv = *(const bf16x8*)(kp + c * 8);
#pragma unroll
    for (int e = 0; e < 8; e++) s += rwb[h * 64 + c * 8 + e] * (float)kv[e];
  }
  cb[id] = s * SCL;
}

// All five weight transposes in one launch: 5 x 256 tiles.
struct TRP { const float* src[5]; __bf16* dst[5]; };
__global__ void __launch_bounds__(256) tr_cvt_all(TRP p) {
  __shared__ float tile[64][65];
  const int id = blockIdx.x;
  const int which = id >> 8;
  const int local = id & 255;
  const int bx = local & 15, by = local >> 4;
  const float* src = p.src[which];
  __bf16* dst = p.dst[which];
  int tx = threadIdx.x & 63, ty = threadIdx.x >> 6;
#pragma unroll
  for (int r = ty; r < 64; r += 4)
    tile[r][tx] = src[(long)(by * 64 + r) * 1024 + bx * 64 + tx];
  __syncthreads();
#pragma unroll
  for (int r = ty; r < 64; r += 4)
    dst[(long)(bx * 64 + r) * 1024 + by * 64 + tx] = (__bf16)tile[tx][r];
}

// -------- fused scores + rel-shift + softmax + PV: 4-wave blocks -----------
// 32 q-rows/block, 8 j-passes of width 256. Strips [32][QSTR3] f16 (qk, x)
// + xB[1024] f16. Per pass: qk+x MFMA + boundary copy + j==i+1 pre-zero ->
// barrier A -> packed-f16 exp2 in place -> barrier B -> PV -> barrier C.
#define QW 256
#define QSTR3 264                         // row stride f16 (256+8)
#define SM_ONE (32 * QSTR3 * 2)           // 16896 B per strip
#define FUSED_SMEM (2 * SM_ONE + 2048)    // 35840 B -> 4 blocks/CU

__global__ void __launch_bounds__(256, 4) fused_k(const __bf16* __restrict__ qb,
                                                  const __bf16* __restrict__ qrr,
                                                  const __bf16* __restrict__ kb,
                                                  const _Float16* __restrict__ vt,
                                                  const __bf16* __restrict__ rb,
                                                  const float* __restrict__ cb,
                                                  __bf16* __restrict__ attnb) {
  extern __shared__ char smem[];
  _Float16* qkS = (_Float16*)smem;              // [32][QSTR3]
  _Float16* xS  = (_Float16*)(smem + SM_ONE);   // [32][QSTR3]
  _Float16* xB  = (_Float16*)(smem + 2 * SM_ONE);  // [1024] boundary row
  __shared__ float sInv[32];

  const int t = threadIdx.x;
  const int w = t >> 6, lane = t & 63, lr = lane & 15, lq = lane >> 4;
  // XCD swizzle: all 64 tiles of a (b,h) on one XCD.
  const int obid = blockIdx.x;
  const int bid = ((obid & 7) << 8) | (obid >> 3);
  const int z  = bid >> 6;
  const int i0 = (bid & 63) << 5;
  const int b = z >> 4, h = z & 15;
  const bool early = (i0 <= 1023);
  const int astart = early ? i0 + 1 : i0;   // 32 MFMA x-rows [astart, astart+32)
  const int grow = early ? 0 : 31;          // boundary strip row
  const int c0   = early ? 0 : i0 + 33;     // boundary col range start

  // B-frags: q rows i0+rg*16+lr, qrr rows astart+rg*16+lr
  bf16x8 fq[2][2], fr[2][2];
#pragma unroll
  for (int rg2 = 0; rg2 < 2; rg2++) {
    const __bf16* qp = qb + (((long)z * 2048 + i0 + rg2 * 16 + lr) << 6) + lq * 8;
    fq[rg2][0] = *(const bf16x8*)qp; fq[rg2][1] = *(const bf16x8*)(qp + 32);
    const __bf16* rp = qrr + (((long)z * 2048 + astart + rg2 * 16 + lr) << 6) + lq * 8;
    fr[rg2][0] = *(const bf16x8*)rp; fr[rg2][1] = *(const bf16x8*)(rp + 32);
  }

  const __bf16* kbz = kb + (((long)z * 2048) << 6);
  const __bf16* rbh = rb + (((long)h * 2048) << 6);
  const float* cbz = cb + (long)z * 2048;
  const _Float16* vtz = vt + (((long)z) << 6) * 2048;

  // ---- boundary row, once per block, coalesced: 8 lanes per column --------
  {
    const int ga    = early ? i0 : i0 + 32;
    const int m0g   = early ? (2047 - i0) : 0;
    int ncols = early ? (i0 + 1) : (2015 - i0);
    if (ncols < 0) ncols = 0;
    const int dl = (t & 7) << 3;          // 8 d's per lane
    bf16x8 qv = *(const bf16x8*)(qrr + (((long)z * 2048 + ga) << 6) + dl);
    for (int c = t >> 3; c < ncols; c += 32) {
      bf16x8 rv = *(const bf16x8*)(rbh + ((long)(m0g + c) << 6) + dl);
      float s = 0.f;
#pragma unroll
      for (int e = 0; e < 8; e++) s += (float)qv[e] * (float)rv[e];
      s += __shfl_xor(s, 1, 64);
      s += __shfl_xor(s, 2, 64);
      s += __shfl_xor(s, 4, 64);
      if ((t & 7) == 0) xB[c] = (_Float16)(s * SCL);
    }
  }
  __syncthreads();   // xB visible to all waves

  const int erow = w * 8 + (lane >> 3);     // exp row for this lane
  const int ecol = (lane & 7) * 16;         // exp col base within half-pass
  const int rg = w >> 1, sl = w & 1;        // PV role: row-group, k-slice

  floatx4 oacc[4];
#pragma unroll
  for (int s = 0; s < 4; s++) oacc[s] = floatx4{0.f, 0.f, 0.f, 0.f};
  float psum = 0.f;

  for (int kp = 0; kp < 8; kp++) {
    const int J0 = kp << 8;

    // qk MFMA (+cb fold): 16 j-tiles, wave does 4. D: row=key-local, col=q-row.
#pragma unroll
    for (int s = 0; s < 4; s++) {
      const int jt = ((w << 2) + s) << 4;     // 0..240
      const __bf16* ap = kbz + ((long)(J0 + jt + lr) << 6) + lq * 8;
      bf16x8 a0 = *(const bf16x8*)ap, a1 = *(const bf16x8*)(ap + 32);
      floatx4 cbv = *(const floatx4*)(cbz + J0 + jt + lq * 4);
      floatx4 c0v{0.f, 0.f, 0.f, 0.f}, c1v{0.f, 0.f, 0.f, 0.f};
      c0v = __builtin_amdgcn_mfma_f32_16x16x32_bf16(a0, fq[0][0], c0v, 0, 0, 0);
      c0v = __builtin_amdgcn_mfma_f32_16x16x32_bf16(a1, fq[0][1], c0v, 0, 0, 0);
      c1v = __builtin_amdgcn_mfma_f32_16x16x32_bf16(a0, fq[1][0], c1v, 0, 0, 0);
      c1v = __builtin_amdgcn_mfma_f32_16x16x32_bf16(a1, fq[1][1], c1v, 0, 0, 0);
      f16x4 s0v, s1v;
#pragma unroll
      for (int g = 0; g < 4; g++) {
        s0v[g] = (_Float16)(c0v[g] * SCL + cbv[g]);
        s1v[g] = (_Float16)(c1v[g] * SCL + cbv[g]);
      }
      *(f16x4*)&qkS[lr * QSTR3 + jt + lq * 4] = s0v;
      *(f16x4*)&qkS[(16 + lr) * QSTR3 + jt + lq * 4] = s1v;
    }

    // x MFMA: m-window = 287 consecutive values -> <=19 tiles over 4 waves;
    // wave-uniform predicate. Scatter with shift pre-applied.
    const int mb = ((J0 - astart - 32) & 2047) & ~15;
#pragma unroll
    for (int s = 0; s < 5; s++) {
      const int mt = w + (s << 2);
      if (mt < 19) {
        const int m0 = (mb + (mt << 4)) & 2047;
        const __bf16* rp2 = rbh + ((long)(m0 + lr) << 6) + lq * 8;
        bf16x8 r0 = *(const bf16x8*)rp2, r1 = *(const bf16x8*)(rp2 + 32);
        floatx4 x0{0.f, 0.f, 0.f, 0.f}, x1{0.f, 0.f, 0.f, 0.f};
        x0 = __builtin_amdgcn_mfma_f32_16x16x32_bf16(r0, fr[0][0], x0, 0, 0, 0);
        x0 = __builtin_amdgcn_mfma_f32_16x16x32_bf16(r1, fr[0][1], x0, 0, 0, 0);
        x1 = __builtin_amdgcn_mfma_f32_16x16x32_bf16(r0, fr[1][0], x1, 0, 0, 0);
        x1 = __builtin_amdgcn_mfma_f32_16x16x32_bf16(r1, fr[1][1], x1, 0, 0, 0);
#pragma unroll
        for (int rg2 = 0; rg2 < 2; rg2++) {
          const int a = astart + (rg2 << 4) + lr;
          const floatx4 ax = rg2 ? x1 : x0;
#pragma unroll
          for (int g = 0; g < 4; g++) {
            const int m = m0 + (lq << 2) + g;
            const int sum = m + a + 1;
            const int j = sum & 2047;
            const int ri = (sum >= 2048) ? (a - i0) : (a - i0 - 1);
            const int jl = j - J0;
            if ((unsigned)ri < 32u && (unsigned)jl < (unsigned)QW)
              xS[ri * QSTR3 + jl] = (_Float16)(ax[g] * SCL);
          }
        }
      }
    }

    // boundary slice: each thread copies 1 col of this pass from xB
    {
      const int j = J0 + t;
      const bool act = early ? (j <= i0) : (j >= c0);
      if (act) xS[grow * QSTR3 + t] = xB[j - c0];
    }
    // pre-zero the j==i+1 hole of each row (collision-free: no scatter or
    // boundary-copy write ever targets (row i, col i+1))
    if (t < 32) {
      const int jl = i0 + t + 1 - J0;
      if ((unsigned)jl < (unsigned)QW) xS[t * QSTR3 + jl] = (_Float16)0.f;
    }
    __syncthreads();   // A: strips complete

    // packed-f16 exp2 in place: row erow, 2 x 16 cols. No selects, no index
    // math: score+x via v_pk_add_f16, exp2 via v_exp_f16, psum via fdot2.
    {
      _Float16* qrow = qkS + erow * QSTR3;
      const _Float16* xrow = xS + erow * QSTR3;
      const f16x2 one2 = {(_Float16)1.f, (_Float16)1.f};
#pragma unroll
      for (int ii = 0; ii < 2; ii++) {
        const int cbase = ii * 128 + ecol;
        f16x8 h0 = *(const f16x8*)(qrow + cbase), h1 = *(const f16x8*)(qrow + cbase + 8);
        f16x8 v0 = *(const f16x8*)(xrow + cbase), v1 = *(const f16x8*)(xrow + cbase + 8);
        f16x8 s0 = h0 + v0, s1 = h1 + v1;
        f16x8 p0, p1;
#pragma unroll
        for (int e2 = 0; e2 < 4; e2++) {
          __half2 a2, b2;
          __builtin_memcpy(&a2, (const char*)&s0 + e2 * 4, 4);
          a2 = h2exp2(a2);
          __builtin_memcpy((char*)&p0 + e2 * 4, &a2, 4);
          f16x2 af2; __builtin_memcpy(&af2, &a2, 4);
          psum = __builtin_amdgcn_fdot2(af2, one2, psum, false);
          __builtin_memcpy(&b2, (const char*)&s1 + e2 * 4, 4);
          b2 = h2exp2(b2);
          __builtin_memcpy((char*)&p1 + e2 * 4, &b2, 4);
          f16x2 bf2; __builtin_memcpy(&bf2, &b2, 4);
          psum = __builtin_amdgcn_fdot2(bf2, one2, psum, false);
        }
        *(f16x8*)(qrow + cbase) = p0;
        *(f16x8*)(qrow + cbase + 8) = p1;
      }
    }
    __syncthreads();   // B: p~ complete

    // PV: wave (rg, sl) contracts keys [J0+sl*128, +128) for rows rg*16..+16
#pragma unroll
    for (int ch = 0; ch < 4; ch++) {
      const int kk = sl * 128 + ch * 32;
      f16x8 af = *(const f16x8*)(qkS + (rg * 16 + lr) * QSTR3 + kk + lq * 8);
#pragma unroll
      for (int sub = 0; sub < 4; sub++) {
        f16x8 bfv = *(const f16x8*)(vtz + (long)(sub * 16 + lr) * 2048 + J0 + kk + lq * 8);
        oacc[sub] = __builtin_amdgcn_mfma_f32_16x16x32_f16(af, bfv, oacc[sub], 0, 0, 0);
      }
    }
    __syncthreads();   // C: strip reads done before next pass overwrites
  }

  // fp32 partials overlay the strips (dead after barrier C of last pass)
  {
    float* sPart = (float*)smem;   // [2*rg+sl][16][64]
#pragma unroll
    for (int sub = 0; sub < 4; sub++)
#pragma unroll
      for (int g = 0; g < 4; g++)
        sPart[((rg << 1) + sl) * 1024 + ((lq << 2) + g) * 64 + sub * 16 + lr] = oacc[sub][g];
  }
  // row sums: reduce 8 col-lanes of each row
#pragma unroll
  for (int o = 1; o < 8; o <<= 1) psum += __shfl_xor(psum, o, 64);
  if ((lane & 7) == 0) sInv[erow] = 1.0f / psum;
  __syncthreads();   // D: partials + sInv complete

  // final: 256 threads x 8 outputs (32 rows x 64 d)
  {
    const float* sPart = (const float*)smem;
    const int r = t >> 3, d0 = (t & 7) << 3;
    const int rg2 = r >> 4, rl = r & 15;
    const float inv = sInv[r];
    bf16x8 ov;
#pragma unroll
    for (int e = 0; e < 8; e++) {
      float acc = sPart[(rg2 << 1) * 1024 + rl * 64 + d0 + e] +
                  sPart[((rg2 << 1) + 1) * 1024 + rl * 64 + d0 + e];
      ov[e] = (__bf16)(acc * inv);
    }
    *(bf16x8*)&attnb[((long)b * 2048 + i0 + r) * 1024 + h * 64 + d0] = ov;
  }
}

extern "C" void kernel_launch(void* const* d_in, const int* in_sizes, int n_in,
                              void* d_out, int out_size, void* d_ws, size_t ws_size,
                              hipStream_t stream) {
  (void)in_sizes; (void)n_in; (void)out_size; (void)ws_size;
  const float* inputs_kv = (const float*)d_in[0];
  const float* inputs_q  = (const float*)d_in[1];
  const float* pos_embed = (const float*)d_in[2];
  const float* Wq_w = (const float*)d_in[3];
  const float* Wq_b = (const float*)d_in[4];
  const float* Wk_w = (const float*)d_in[5];
  const float* Wk_b = (const float*)d_in[6];
  const float* Wv_w = (const float*)d_in[7];
  const float* Wv_b = (const float*)d_in[8];
  const float* Wr_w = (const float*)d_in[9];
  const float* rwb  = (const float*)d_in[10];
  const float* rrb  = (const float*)d_in[11];
  const float* Wo_w = (const float*)d_in[12];
  const float* Wo_b = (const float*)d_in[13];

  char* ws = (char*)d_ws;
  const long MB = 1 << 20;
  __bf16* Wtq = (__bf16*)(ws + 0 * MB);
  __bf16* Wtk = (__bf16*)(ws + 2 * MB);
  __bf16* Wtv = (__bf16*)(ws + 4 * MB);
  __bf16* Wtr = (__bf16*)(ws + 6 * MB);
  __bf16* Wto = (__bf16*)(ws + 8 * MB);
  __bf16* qb  = (__bf16*)(ws + 10 * MB);
  __bf16* qrr = (__bf16*)(ws + 18 * MB);
  __bf16* kb  = (__bf16*)(ws + 26 * MB);
  _Float16* vt = (_Float16*)(ws + 34 * MB);
  __bf16* rb  = (__bf16*)(ws + 42 * MB);
  float*  cb  = (float*)(ws + 46 * MB);               // 256 KB
  __bf16* attnb = (__bf16*)(ws + 47 * MB);            // 8 MB bf16 attention out

  dim3 blk(256);

  TRP tp{};
  tp.src[0] = Wq_w; tp.dst[0] = Wtq;
  tp.src[1] = Wk_w; tp.dst[1] = Wtk;
  tp.src[2] = Wv_w; tp.dst[2] = Wtv;
  tp.src[3] = Wr_w; tp.dst[3] = Wtr;
  tp.src[4] = Wo_w; tp.dst[4] = Wto;
  tr_cvt_all<<<dim3(1280), blk, 0, stream>>>(tp);

  QPAll q{};
  q.qin = inputs_q; q.kvin = inputs_kv; q.pos = pos_embed;
  q.Wtq = Wtq; q.Wtk = Wtk; q.Wtv = Wtv; q.Wtr = Wtr;
  q.bq = Wq_b; q.bk = Wk_b; q.bv = Wv_b; q.rrb = rrb;
  q.qb = qb; q.qrr = qrr; q.kb = kb; q.rb = rb; q.vt = vt;
  qkvr_k<<<dim3(896), blk, 0, stream>>>(q);

  cb_k<<<dim3(256), blk, 0, stream>>>(kb, rwb, cb);

  fused_k<<<dim3(2048), dim3(256), FUSED_SMEM, stream>>>(qb, qrr, kb, vt, rb, cb, attnb);

  // Output projection: d_out = attn(bf16) @ Wo + bo
  GP o{};
  o.A = attnb; o.B = Wto; o.lda = 1024; o.ldb = 1024; o.K = 1024;
  o.bias = Wo_b; o.outF = (float*)d_out;
  gemm_o<<<dim3(8, 32), blk, 0, stream>>>(o);
}